// Round 9
// baseline (200.228 us; speedup 1.0000x reference)
//
#include <hip/hip_runtime.h>
#include <cstdint>

typedef unsigned long long ull;

#define N_BOX 8192
#define CH 512        // chunk size
#define WPC 8         // words per chunk
#define NCH 16        // chunks

// ---------------- workspace layout ----------------
// TB (distance>=2 transposed col-blocks): 53760 rows * 64 B = 3,440,640 @ 0
// TC (superdiagonal transposed blocks):   15 * 32 KB        =   491,520 @ 3,440,640
// TD (per-chunk diagonal tables):         16 * 32 KB        =   524,288 @ 3,932,160
// boxes4 : 131072 @ 4,456,448
// scores : 32768  @ 4,587,520
// ctrl   : flags on private 128 B lines @ 4,620,288
//          flagK[c] = int c*32 ; vb = int 512 ; flagP[c] = int 1024+c*32
// keptg  : 16 chunks * 16 ull (128 B stride) @ 4,689,920
// pusha  : 16 chunks * 16 ull (128 B stride) @ 4,691,968
// TDC    : in-word COLUMN table, 16 chunks * 512 ull = 64 KB @ 4,694,144
#define OFF_TB     0
#define OFF_TC     3440640
#define OFF_TD     3932160
#define OFF_BOXES  4456448
#define OFF_SCORES 4587520
#define OFF_CTRL   4620288
#define OFF_KEPT   4689920
#define OFF_PUSH   4691968
#define OFF_TDC    4694144

#define CTRL_VB    512    // int index of vb
#define PFLAG      1024   // int index base of push flags (+c*32)
#define KSTRIDE    16     // ull stride per chunk in keptg/pusha

// Agent(device)-scope accessors. R7-proven: RELAXED spins (sc1, read MALL,
// no per-poll L2 invalidate — acquire spins were the R6 5us/hop storm);
// release stores order the preceding sc1 data stores.
#define A_LD(p)    __hip_atomic_load((p), __ATOMIC_RELAXED, __HIP_MEMORY_SCOPE_AGENT)
#define A_ST(p,v)  __hip_atomic_store((p), (v), __ATOMIC_RELAXED, __HIP_MEMORY_SCOPE_AGENT)
#define A_STR(p,v) __hip_atomic_store((p), (v), __ATOMIC_RELEASE, __HIP_MEMORY_SCOPE_AGENT)

// TB rows for source chunk c' cover j >= CH*(c'+2): 7168-512c' rows (c'=0..13)
__device__ __forceinline__ int rows_before2(int c) {
    return 7424 * c - 256 * c * c;   // sum_{c'<c} (7168 - 512c')
}

__device__ __forceinline__ ull make_key(float s, int idx) {
    // positive floats: bit pattern is order-preserving. Reversed index in the
    // low 13 bits reproduces stable argsort(-conf): equal conf -> lower index first.
    return (((ull)__float_as_uint(s)) << 13) | (ull)(8191 - idx);
}

__device__ __forceinline__ float box_area(float4 b) {
    return __fmul_rn(__fsub_rn(b.z, b.x), __fsub_rn(b.w, b.y));
}

// exact replica of reference IoU rounding (_rn ops block FMA contraction); symmetric.
__device__ __forceinline__ bool iou_gt_half(float4 a, float aarea, float4 b, float barea) {
    float ix1 = fmaxf(a.x, b.x);
    float iy1 = fmaxf(a.y, b.y);
    float ix2 = fminf(a.z, b.z);
    float iy2 = fminf(a.w, b.w);
    float iw = fmaxf(__fsub_rn(ix2, ix1), 0.0f);
    float ih = fmaxf(__fsub_rn(iy2, iy1), 0.0f);
    float inter = __fmul_rn(iw, ih);
    float uni = __fsub_rn(__fadd_rn(aarea, barea), inter);
    float iou = __fdiv_rn(inter, fmaxf(uni, 1e-9f));
    return iou > 0.5f;
}

// kA: fused max + rank + scatter (R3/R7-proven form, reverted from R8's
// register-blocked variant — that one was neutral in steady state and showed
// a 41us cold-start outlier). Rank via the PROVEN immediate-offset LDS loop.
// Block 0 zeroes the k5 chain flags (flagK + flagP) and publishes vb.
__global__ __launch_bounds__(256) void k123_rank_scatter(const float* __restrict__ in,
                                                         float4* __restrict__ boxes4,
                                                         float* __restrict__ scores,
                                                         int* __restrict__ ctrl) {
    __shared__ ull keys[N_BOX];        // 64 KB
    __shared__ float wm[4];
    __shared__ int wv[4];
    int t = threadIdx.x;
    int bx = blockIdx.x;

    float cf[32];
    float m = 0.0f;                    // conf >= 0 so 0-seed is safe
    #pragma unroll
    for (int r = 0; r < 32; ++r) {
        cf[r] = in[(r * 256 + t) * 5 + 4];
        m = fmaxf(m, cf[r]);
    }
    for (int off = 32; off; off >>= 1) m = fmaxf(m, __shfl_down(m, off));
    if ((t & 63) == 0) wm[t >> 6] = m;
    __syncthreads();
    float maxc = fmaxf(fmaxf(wm[0], wm[1]), fmaxf(wm[2], wm[3]));

    #pragma unroll
    for (int r = 0; r < 32; ++r) {
        int k = r * 256 + t;
        keys[k] = make_key(__fdiv_rn(cf[r], maxc), k);
    }
    __syncthreads();

    int il = t >> 3, seg = t & 7;
    int i = bx * 32 + il;
    ull ki = keys[i];
    const ull* kb = keys + seg;
    int cnt = 0;
    #pragma unroll 8
    for (int cc = 0; cc < 1024; ++cc)
        cnt += (kb[cc * 8] > ki) ? 1 : 0;
    cnt += __shfl_down(cnt, 4, 8);
    cnt += __shfl_down(cnt, 2, 8);
    cnt += __shfl_down(cnt, 1, 8);

    if (seg == 0) {
        int r = cnt;                               // descending-sort position
        float cx = in[i * 5 + 0];
        float cy = in[i * 5 + 1];
        float w  = in[i * 5 + 2];
        float h  = in[i * 5 + 3];
        float s  = __fdiv_rn(in[i * 5 + 4], maxc);
        float4 b;
        b.x = __fsub_rn(cx, __fmul_rn(w, 0.5f));
        b.y = __fsub_rn(cy, __fmul_rn(h, 0.5f));
        b.z = __fadd_rn(cx, __fmul_rn(w, 0.5f));
        b.w = __fadd_rn(cy, __fmul_rn(h, 0.5f));
        boxes4[r] = b;
        scores[r] = s;
    }

    // block 0: vb + zero chain flags (poisoned workspace)
    if (bx == 0) {
        const ull kthr = ((ull)0x3F000000u) << 13;   // s >= 0.5 boundary
        int cv = 0;
        for (int k = t; k < N_BOX; k += 256) cv += (keys[k] >= kthr) ? 1 : 0;
        for (int off = 32; off; off >>= 1) cv += __shfl_down(cv, off);
        if ((t & 63) == 0) wv[t >> 6] = cv;
        if (t < NCH) ctrl[t * 32] = 0;               // flagK
        if (t < NCH) ctrl[PFLAG + t * 32] = 0;       // flagP
        __syncthreads();
        if (t == 0) ctrl[CTRL_VB] = wv[0] + wv[1] + wv[2] + wv[3];
    }
}

// K4: build suppression bit tables. R7 structure + NEW mode 3 (TDC): the
// in-word COLUMN table TDC[c][s] = bitmask of same-word boxes j>k that source
// s suppresses — the transpose of TD's diagonal, enabling k5's serial-greedy
// scan. 2208 blocks: TB 0..1679, TC 1680..1919, TD 1920..2175, TDC 2176..2207.
// IoU loops bank-STAGGERED (proven bit-identical R5-R8).
__global__ __launch_bounds__(256) void k4_build(const float4* __restrict__ boxes4,
                                                const float* __restrict__ scores,
                                                ull* __restrict__ TB,
                                                ull* __restrict__ TC,
                                                ull* __restrict__ TD,
                                                ull* __restrict__ TDC) {
    __shared__ float4 sb[CH];
    __shared__ float sa[CH];
    int bid = blockIdx.x;
    int t = threadIdx.x;
    int c;
    int mode;   // 0=TB, 1=TC, 2=TD, 3=TDC
    int j0;     // TB: global j tile start; TC/TD: local jl tile start; TDC: source base
    if (bid >= 2176) {
        mode = 3;
        int d = bid - 2176;
        c = d >> 1;
        j0 = (d & 1) * 256;
    } else if (bid >= 1920) {
        mode = 2;
        int d = bid - 1920;
        c = d >> 4;
        j0 = (d & 15) * 32;
    } else if (bid >= 1680) {
        mode = 1;
        int d = bid - 1680;
        c = d >> 4;          // 0..14
        j0 = (d & 15) * 32;
    } else {
        mode = 0;
        c = 0;
        int rem = bid;
        while (rem >= 224 - 16 * c) { rem -= 224 - 16 * c; ++c; }
        j0 = CH * (c + 2) + rem * 32;
    }
    if (scores[c * CH] < 0.5f) return;               // source chunk never a suppressor
    if (mode == 0 && scores[j0] < 0.5f) return;      // j-tile never alive (desc scores)

    for (int i = t; i < CH; i += 256) {
        float4 b = boxes4[c * CH + i];
        sb[i] = b;
        sa[i] = box_area(b);
    }
    __syncthreads();

    if (mode == 3) {
        // source s suppresses which same-word targets j>k?
        int s = j0 + t;                // 0..511 local source index
        int w = s >> 6, k = s & 63;
        float4 me = sb[s];
        float ma = sa[s];
        ull bits = 0;
        #pragma unroll 8
        for (int mth = 0; mth < 64; ++mth) {
            int j = (mth + k) & 63;    // lane-staggered: distinct banks per wave
            if (j > k &&
                iou_gt_half(sb[w * 64 + j], sa[w * 64 + j], me, ma))
                bits |= 1ull << j;
        }
        TDC[c * 512 + s] = bits;
        return;
    }

    int w = t & 7;
    int r = t >> 3;          // 0..31 local row
    int jl = j0 + r;         // mode 2/1: local row; mode 0: global j
    float4 me;
    float ma;
    int lim = 64;
    if (mode == 2) {
        me = sb[jl];
        ma = sa[jl];
        int wj = jl >> 6;
        lim = (w < wj) ? 64 : ((w == wj) ? (jl & 63) : 0);
    } else if (mode == 1) {
        me = boxes4[CH * (c + 1) + jl];
        ma = box_area(me);
    } else {
        me = boxes4[jl];
        ma = box_area(me);
    }
    ull bits = 0;
    #pragma unroll 8
    for (int k = 0; k < 64; ++k) {
        int kk = (k + w) & 63;         // bank stagger, bit-identical output
        if (kk < lim &&
            iou_gt_half(sb[w * 64 + kk], sa[w * 64 + kk], me, ma))
            bits |= 1ull << kk;
    }
    if (mode == 2)      TD[c * 4096 + w * 512 + jl] = bits;
    else if (mode == 1) TC[c * 4096 + w * 512 + jl] = bits;
    else TB[(size_t)(rows_before2(c) + (jl - CH * (c + 2))) * WPC + w] = bits;
}

// K5: pipelined multi-block greedy NMS, block c owns chunk c. R7-verbatim
// structure and handoff (relaxed spins, producer-push, release publishes).
// Round-9 change: the in-word scan is SERIAL GREEDY with the TDC column
// table instead of the ballot fixpoint. The lowest alive box is always kept
// (its potential suppressors are lower-indexed alive boxes — none exist);
// one 64-bit shfl fetches its suppression column; one AND kills the word's
// victims. Iterations = #kept (small under dense suppression) vs the old
// 2-ballots-x-chain-depth rounds. tdc[8] is prefetched into wave-0 registers
// BEFORE the flag waits (global-load latency hidden). Cross-word ballot
// applies and TB/TC phases unchanged.
__global__ __launch_bounds__(1024) void k5_nms(const float4* __restrict__ boxes4,
                                               const float* __restrict__ scores,
                                               const ull* __restrict__ TBg,
                                               const ull* __restrict__ TCg,
                                               const ull* __restrict__ TDg,
                                               const ull* __restrict__ TDCg,
                                               ull* __restrict__ keptg,
                                               ull* __restrict__ pusha,
                                               int* __restrict__ ctrl,
                                               float* __restrict__ out) {
    __shared__ ull TDs[CH * WPC];      // 32 KB: TD[c]
    __shared__ ull TCs[CH * WPC];      // 32 KB: TC[c]  (push source, c -> c+1)
    __shared__ ull kwsh[WPC];
    __shared__ ull darr[WPC];
    __shared__ unsigned amask[16];     // 512 alive bits for own chunk
    int c = blockIdx.x;
    int t = threadIdx.x;
    int lane = t & 63;
    int wave = t >> 6;
    int vb = ctrl[CTRL_VB];
    int nchv = (vb + CH - 1) / CH;

    if (c < nchv) {
        // ---- prefetch TDC columns into wave-0 registers (hidden latency) ----
        ull tdc[WPC];
        if (wave == 0) {
            #pragma unroll
            for (int w = 0; w < WPC; ++w)
                tdc[w] = TDCg[c * 512 + w * 64 + lane];
        }
        // ---- stage TD[c] (and TC[c] if we will push); init alive mask ----
        {
            const ulonglong2* src = (const ulonglong2*)(TDg + (size_t)c * CH * WPC);
            ulonglong2* dst = (ulonglong2*)TDs;
            #pragma unroll
            for (int i2 = t; i2 < CH * WPC / 2; i2 += 1024) dst[i2] = src[i2];
        }
        if (c + 1 < nchv) {
            const ulonglong2* src = (const ulonglong2*)(TCg + (size_t)c * CH * WPC);
            ulonglong2* dst = (ulonglong2*)TCs;
            #pragma unroll
            for (int i2 = t; i2 < CH * WPC / 2; i2 += 1024) dst[i2] = src[i2];
        }
        if (t < 16) {
            int n = vb - (c * 16 + t) * 32;
            amask[t] = (n >= 32) ? 0xffffffffu : ((n <= 0) ? 0u : ((1u << n) - 1u));
        }
        __syncthreads();

        // ---- TB applies: kept[cp] -> own chunk, cp = 0..c-2 ----
        for (int cp = 0; cp + 2 <= c; ++cp) {
            if (wave == 0) {
                if (lane == 0) { while (A_LD(&ctrl[cp * 32]) != 1) {} }
                // reconvergence: lanes 0-7 load only after the spin exits
                if (lane < WPC) kwsh[lane] = A_LD(&keptg[cp * KSTRIDE + lane]);
            }
            __syncthreads();
            ull anyk = kwsh[0] | kwsh[1] | kwsh[2] | kwsh[3] |
                       kwsh[4] | kwsh[5] | kwsh[6] | kwsh[7];
            if (anyk && t < CH) {
                if ((amask[t >> 5] >> (t & 31)) & 1u) {
                    const ull* row = TBg +
                        (size_t)(rows_before2(cp) + (c * CH + t - CH * (cp + 2))) * WPC;
                    ull a = 0;
                    #pragma unroll
                    for (int q = 0; q < WPC; ++q) a |= row[q] & kwsh[q];
                    if (a) atomicAnd(&amask[t >> 5], ~(1u << (t & 31)));
                }
            }
            __syncthreads();
        }

        // ---- pushed TC suppression from owner c-1 (replaces local TC apply) ----
        if (c > 0) {
            if (wave == 0) {
                if (lane == 0) { while (A_LD(&ctrl[PFLAG + c * 32]) != 1) {} }
                if (lane < WPC) kwsh[lane] = A_LD(&pusha[c * KSTRIDE + lane]);
            }
            __syncthreads();
            if (t < WPC) {
                ull s = kwsh[t];
                amask[2 * t]     &= ~(unsigned)s;
                amask[2 * t + 1] &= ~(unsigned)(s >> 32);
            }
            __syncthreads();
        }

        // ---- scan own chunk (wave 0): serial greedy per word, then publish ----
        if (wave == 0) {
            ull alive[WPC];
            #pragma unroll
            for (int w = 0; w < WPC; ++w)
                alive[w] = (ull)amask[2 * w] | ((ull)amask[2 * w + 1] << 32);
            const ull* T = TDs;
            #pragma unroll
            for (int w = 0; w < WPC; ++w) {
                ull a2 = alive[w];
                if (!a2) continue;
                ull Tc[WPC];
                #pragma unroll
                for (int j = 0; j < WPC; ++j)
                    if (j > w) Tc[j] = T[w * 512 + j * 64 + lane];
                // serial greedy: lowest alive is kept; kill its victims
                ull kept = 0;
                while (a2) {
                    int k = __builtin_ctzll(a2);
                    kept |= 1ull << k;
                    ull sc = __shfl(tdc[w], k);   // lane k's suppression column
                    a2 &= ~sc;
                    a2 &= ~(1ull << k);
                }
                alive[w] = kept;
                #pragma unroll
                for (int j = 0; j < WPC; ++j) {
                    if (j <= w) continue;
                    if (!alive[j]) continue;
                    alive[j] &= ~__ballot((Tc[j] & kept) != 0);
                }
            }
            if (lane == 0) {
                #pragma unroll
                for (int w = 0; w < WPC; ++w) {
                    A_ST(&keptg[c * KSTRIDE + w], alive[w]);
                    amask[2 * w]     = (unsigned)alive[w];
                    amask[2 * w + 1] = (unsigned)(alive[w] >> 32);
                }
                A_STR(&ctrl[c * 32], 1);          // release orders the 8 stores
            }
        }
        __syncthreads();

        // ---- producer push: TC apply for chunk c+1, publish suppression ----
        if (c + 1 < nchv) {
            if (wave < WPC) {
                ull kw[WPC];
                #pragma unroll
                for (int w = 0; w < WPC; ++w)
                    kw[w] = (ull)amask[2 * w] | ((ull)amask[2 * w + 1] << 32);
                bool dead = false;
                #pragma unroll
                for (int w = 0; w < WPC; ++w) {
                    if (kw[w]) dead |= (TCs[w * 512 + wave * 64 + lane] & kw[w]) != 0ull;
                }
                ull d = __ballot(dead);
                if (lane == 0) darr[wave] = d;
            }
            __syncthreads();
            if (t == 0) {
                #pragma unroll
                for (int w = 0; w < WPC; ++w)
                    A_ST(&pusha[(c + 1) * KSTRIDE + w], darr[w]);
                A_STR(&ctrl[PFLAG + (c + 1) * 32], 1);   // release orders them
            }
        }
        __syncthreads();
    } else {
        if (t < 16) amask[t] = 0u;
        __syncthreads();
    }

    // ---- epilogue: write own 512 output rows ----
    if (t < CH) {
        int j = c * CH + t;
        bool kept = (amask[t >> 5] >> (t & 31)) & 1u;
        float4 b = boxes4[j];
        float s = scores[j];
        out[j * 5 + 0] = kept ? b.x : 0.0f;
        out[j * 5 + 1] = kept ? b.y : 0.0f;
        out[j * 5 + 2] = kept ? b.z : 0.0f;
        out[j * 5 + 3] = kept ? b.w : 0.0f;
        out[j * 5 + 4] = kept ? s   : 0.0f;
    }
}

extern "C" void kernel_launch(void* const* d_in, const int* in_sizes, int n_in,
                              void* d_out, int out_size, void* d_ws, size_t ws_size,
                              hipStream_t stream) {
    const float* in = (const float*)d_in[0];
    char* ws = (char*)d_ws;
    ull* TB        = (ull*)(ws + OFF_TB);
    ull* TC        = (ull*)(ws + OFF_TC);
    ull* TD        = (ull*)(ws + OFF_TD);
    float4* boxes4 = (float4*)(ws + OFF_BOXES);
    float* scores  = (float*)(ws + OFF_SCORES);
    int* ctrl      = (int*)(ws + OFF_CTRL);
    ull* keptg     = (ull*)(ws + OFF_KEPT);
    ull* pusha     = (ull*)(ws + OFF_PUSH);
    ull* TDC       = (ull*)(ws + OFF_TDC);
    float* out     = (float*)d_out;

    k123_rank_scatter<<<256, 256, 0, stream>>>(in, boxes4, scores, ctrl);
    k4_build<<<2208, 256, 0, stream>>>(boxes4, scores, TB, TC, TD, TDC);
    k5_nms<<<NCH, 1024, 0, stream>>>(boxes4, scores, TB, TC, TD, TDC,
                                     keptg, pusha, ctrl, out);
}

// Round 10
// 120.907 us; speedup vs baseline: 1.6561x; 1.6561x over previous
//
#include <hip/hip_runtime.h>
#include <cstdint>

typedef unsigned long long ull;

#define N_BOX 8192
#define CH 512        // chunk size
#define WPC 8         // words per chunk
#define NCH 16        // chunks

// ---------------- workspace layout ----------------
// TB (distance>=2 transposed col-blocks): 53760 rows * 64 B = 3,440,640 @ 0
// TC (superdiagonal transposed blocks):   15 * 32 KB        =   491,520 @ 3,440,640
// TD (per-chunk diagonal tables):         16 * 32 KB        =   524,288 @ 3,932,160
// boxes4 : 131072 @ 4,456,448
// scores : 32768  @ 4,587,520
// ctrl   : flags on private 128 B lines @ 4,620,288
//          flagK[c] = int c*32 ; vb = int 512 ; flagP[c] = int 1024+c*32
// keptg  : 16 chunks * 16 ull (128 B stride) @ 4,689,920
// pusha  : 16 chunks * 16 ull (128 B stride) @ 4,691,968
#define OFF_TB     0
#define OFF_TC     3440640
#define OFF_TD     3932160
#define OFF_BOXES  4456448
#define OFF_SCORES 4587520
#define OFF_CTRL   4620288
#define OFF_KEPT   4689920
#define OFF_PUSH   4691968

#define CTRL_VB    512    // int index of vb
#define PFLAG      1024   // int index base of push flags (+c*32)
#define KSTRIDE    16     // ull stride per chunk in keptg/pusha

// Agent(device)-scope accessors. R7-proven: RELAXED spins (sc1, read MALL,
// no per-poll L2 invalidate — acquire spins were the R6 5us/hop storm);
// release stores order the preceding sc1 data stores.
// R9 lesson: the in-word scan must stay the BALLOT FIXPOINT — suppression is
// sparse for this data, so kept-count is high and any serial-per-kept-box
// loop (R9: ctz+bpermute chain) costs ~4x the fixpoint's 2-3 rounds.
#define A_LD(p)    __hip_atomic_load((p), __ATOMIC_RELAXED, __HIP_MEMORY_SCOPE_AGENT)
#define A_ST(p,v)  __hip_atomic_store((p), (v), __ATOMIC_RELAXED, __HIP_MEMORY_SCOPE_AGENT)
#define A_STR(p,v) __hip_atomic_store((p), (v), __ATOMIC_RELEASE, __HIP_MEMORY_SCOPE_AGENT)

// TB rows for source chunk c' cover j >= CH*(c'+2): 7168-512c' rows (c'=0..13)
__device__ __forceinline__ int rows_before2(int c) {
    return 7424 * c - 256 * c * c;   // sum_{c'<c} (7168 - 512c')
}

__device__ __forceinline__ ull make_key(float s, int idx) {
    // positive floats: bit pattern is order-preserving. Reversed index in the
    // low 13 bits reproduces stable argsort(-conf): equal conf -> lower index first.
    return (((ull)__float_as_uint(s)) << 13) | (ull)(8191 - idx);
}

__device__ __forceinline__ float box_area(float4 b) {
    return __fmul_rn(__fsub_rn(b.z, b.x), __fsub_rn(b.w, b.y));
}

// exact replica of reference IoU rounding (_rn ops block FMA contraction); symmetric.
__device__ __forceinline__ bool iou_gt_half(float4 a, float aarea, float4 b, float barea) {
    float ix1 = fmaxf(a.x, b.x);
    float iy1 = fmaxf(a.y, b.y);
    float ix2 = fminf(a.z, b.z);
    float iy2 = fminf(a.w, b.w);
    float iw = fmaxf(__fsub_rn(ix2, ix1), 0.0f);
    float ih = fmaxf(__fsub_rn(iy2, iy1), 0.0f);
    float inter = __fmul_rn(iw, ih);
    float uni = __fsub_rn(__fadd_rn(aarea, barea), inter);
    float iou = __fdiv_rn(inter, fmaxf(uni, 1e-9f));
    return iou > 0.5f;
}

// kA: fused max + rank + scatter (R3/R7-proven). Block bx owns i in
// [bx*32, bx*32+32); rank via the PROVEN immediate-offset LDS loop (u64 key
// compare, LDS addr = base + compile-time immediate — pipelines; per-lane
// dynamic addressing was the R2 87us disaster).
// Block 0 zeroes the k5 chain flags (flagK + flagP) and publishes vb.
__global__ __launch_bounds__(256) void k123_rank_scatter(const float* __restrict__ in,
                                                         float4* __restrict__ boxes4,
                                                         float* __restrict__ scores,
                                                         int* __restrict__ ctrl) {
    __shared__ ull keys[N_BOX];        // 64 KB
    __shared__ float wm[4];
    __shared__ int wv[4];
    int t = threadIdx.x;
    int bx = blockIdx.x;

    float cf[32];
    float m = 0.0f;                    // conf >= 0 so 0-seed is safe
    #pragma unroll
    for (int r = 0; r < 32; ++r) {
        cf[r] = in[(r * 256 + t) * 5 + 4];
        m = fmaxf(m, cf[r]);
    }
    for (int off = 32; off; off >>= 1) m = fmaxf(m, __shfl_down(m, off));
    if ((t & 63) == 0) wm[t >> 6] = m;
    __syncthreads();
    float maxc = fmaxf(fmaxf(wm[0], wm[1]), fmaxf(wm[2], wm[3]));

    #pragma unroll
    for (int r = 0; r < 32; ++r) {
        int k = r * 256 + t;
        keys[k] = make_key(__fdiv_rn(cf[r], maxc), k);
    }
    __syncthreads();

    int il = t >> 3, seg = t & 7;
    int i = bx * 32 + il;
    ull ki = keys[i];
    const ull* kb = keys + seg;
    int cnt = 0;
    #pragma unroll 8
    for (int cc = 0; cc < 1024; ++cc)
        cnt += (kb[cc * 8] > ki) ? 1 : 0;
    cnt += __shfl_down(cnt, 4, 8);
    cnt += __shfl_down(cnt, 2, 8);
    cnt += __shfl_down(cnt, 1, 8);

    if (seg == 0) {
        int r = cnt;                               // descending-sort position
        float cx = in[i * 5 + 0];
        float cy = in[i * 5 + 1];
        float w  = in[i * 5 + 2];
        float h  = in[i * 5 + 3];
        float s  = __fdiv_rn(in[i * 5 + 4], maxc);
        float4 b;
        b.x = __fsub_rn(cx, __fmul_rn(w, 0.5f));
        b.y = __fsub_rn(cy, __fmul_rn(h, 0.5f));
        b.z = __fadd_rn(cx, __fmul_rn(w, 0.5f));
        b.w = __fadd_rn(cy, __fmul_rn(h, 0.5f));
        boxes4[r] = b;
        scores[r] = s;
    }

    // block 0: vb + zero chain flags (poisoned workspace)
    if (bx == 0) {
        const ull kthr = ((ull)0x3F000000u) << 13;   // s >= 0.5 boundary
        int cv = 0;
        for (int k = t; k < N_BOX; k += 256) cv += (keys[k] >= kthr) ? 1 : 0;
        for (int off = 32; off; off >>= 1) cv += __shfl_down(cv, off);
        if ((t & 63) == 0) wv[t >> 6] = cv;
        if (t < NCH) ctrl[t * 32] = 0;               // flagK
        if (t < NCH) ctrl[PFLAG + t * 32] = 0;       // flagP
        __syncthreads();
        if (t == 0) ctrl[CTRL_VB] = wv[0] + wv[1] + wv[2] + wv[3];
    }
}

// K4: build suppression bit tables (R7-verbatim, passed). 2176 blocks / 8 per
// CU TLP; IoU inner loop bank-STAGGERED (kk=(k+w)&63, bit-identical output).
__global__ __launch_bounds__(256) void k4_build(const float4* __restrict__ boxes4,
                                                const float* __restrict__ scores,
                                                ull* __restrict__ TB,
                                                ull* __restrict__ TC,
                                                ull* __restrict__ TD) {
    __shared__ float4 sb[CH];
    __shared__ float sa[CH];
    int bid = blockIdx.x;
    int t = threadIdx.x;
    int c;
    int mode;   // 0=TB, 1=TC, 2=TD
    int j0;     // TB: global j tile start; TC/TD: local jl tile start
    if (bid >= 1920) {
        mode = 2;
        int d = bid - 1920;
        c = d >> 4;
        j0 = (d & 15) * 32;
    } else if (bid >= 1680) {
        mode = 1;
        int d = bid - 1680;
        c = d >> 4;          // 0..14
        j0 = (d & 15) * 32;
    } else {
        mode = 0;
        c = 0;
        int rem = bid;
        while (rem >= 224 - 16 * c) { rem -= 224 - 16 * c; ++c; }
        j0 = CH * (c + 2) + rem * 32;
    }
    if (scores[c * CH] < 0.5f) return;               // source chunk never a suppressor
    if (mode == 0 && scores[j0] < 0.5f) return;      // j-tile never alive (desc scores)

    for (int i = t; i < CH; i += 256) {
        float4 b = boxes4[c * CH + i];
        sb[i] = b;
        sa[i] = box_area(b);
    }
    __syncthreads();

    int w = t & 7;
    int r = t >> 3;          // 0..31 local row
    int jl = j0 + r;         // mode 2/1: local row; mode 0: global j
    float4 me;
    float ma;
    int lim = 64;
    if (mode == 2) {
        me = sb[jl];
        ma = sa[jl];
        int wj = jl >> 6;
        lim = (w < wj) ? 64 : ((w == wj) ? (jl & 63) : 0);
    } else if (mode == 1) {
        me = boxes4[CH * (c + 1) + jl];
        ma = box_area(me);
    } else {
        me = boxes4[jl];
        ma = box_area(me);
    }
    ull bits = 0;
    #pragma unroll 8
    for (int k = 0; k < 64; ++k) {
        int kk = (k + w) & 63;         // bank stagger, bit-identical output
        if (kk < lim &&
            iou_gt_half(sb[w * 64 + kk], sa[w * 64 + kk], me, ma))
            bits |= 1ull << kk;
    }
    if (mode == 2)      TD[c * 4096 + w * 512 + jl] = bits;
    else if (mode == 1) TC[c * 4096 + w * 512 + jl] = bits;
    else TB[(size_t)(rows_before2(c) + (jl - CH * (c + 2))) * WPC + w] = bits;
}

// K5: pipelined multi-block greedy NMS, block c owns chunk c. R7-verbatim
// (session-best 121.4us): producer-push handoff, relaxed spins, release
// publishes, BALLOT-FIXPOINT in-word scan (fast in the sparse-suppression
// regime this data is in — see R9 lesson above).
__global__ __launch_bounds__(1024) void k5_nms(const float4* __restrict__ boxes4,
                                               const float* __restrict__ scores,
                                               const ull* __restrict__ TBg,
                                               const ull* __restrict__ TCg,
                                               const ull* __restrict__ TDg,
                                               ull* __restrict__ keptg,
                                               ull* __restrict__ pusha,
                                               int* __restrict__ ctrl,
                                               float* __restrict__ out) {
    __shared__ ull TDs[CH * WPC];      // 32 KB: TD[c]
    __shared__ ull TCs[CH * WPC];      // 32 KB: TC[c]  (push source, c -> c+1)
    __shared__ ull kwsh[WPC];
    __shared__ ull darr[WPC];
    __shared__ unsigned amask[16];     // 512 alive bits for own chunk
    int c = blockIdx.x;
    int t = threadIdx.x;
    int lane = t & 63;
    int wave = t >> 6;
    int vb = ctrl[CTRL_VB];
    int nchv = (vb + CH - 1) / CH;

    if (c < nchv) {
        // ---- stage TD[c] (and TC[c] if we will push); init alive mask ----
        {
            const ulonglong2* src = (const ulonglong2*)(TDg + (size_t)c * CH * WPC);
            ulonglong2* dst = (ulonglong2*)TDs;
            #pragma unroll
            for (int i2 = t; i2 < CH * WPC / 2; i2 += 1024) dst[i2] = src[i2];
        }
        if (c + 1 < nchv) {
            const ulonglong2* src = (const ulonglong2*)(TCg + (size_t)c * CH * WPC);
            ulonglong2* dst = (ulonglong2*)TCs;
            #pragma unroll
            for (int i2 = t; i2 < CH * WPC / 2; i2 += 1024) dst[i2] = src[i2];
        }
        if (t < 16) {
            int n = vb - (c * 16 + t) * 32;
            amask[t] = (n >= 32) ? 0xffffffffu : ((n <= 0) ? 0u : ((1u << n) - 1u));
        }
        __syncthreads();

        // ---- TB applies: kept[cp] -> own chunk, cp = 0..c-2 ----
        for (int cp = 0; cp + 2 <= c; ++cp) {
            if (wave == 0) {
                if (lane == 0) { while (A_LD(&ctrl[cp * 32]) != 1) {} }
                // reconvergence: lanes 0-7 load only after the spin exits
                if (lane < WPC) kwsh[lane] = A_LD(&keptg[cp * KSTRIDE + lane]);
            }
            __syncthreads();
            ull anyk = kwsh[0] | kwsh[1] | kwsh[2] | kwsh[3] |
                       kwsh[4] | kwsh[5] | kwsh[6] | kwsh[7];
            if (anyk && t < CH) {
                if ((amask[t >> 5] >> (t & 31)) & 1u) {
                    const ull* row = TBg +
                        (size_t)(rows_before2(cp) + (c * CH + t - CH * (cp + 2))) * WPC;
                    ull a = 0;
                    #pragma unroll
                    for (int q = 0; q < WPC; ++q) a |= row[q] & kwsh[q];
                    if (a) atomicAnd(&amask[t >> 5], ~(1u << (t & 31)));
                }
            }
            __syncthreads();
        }

        // ---- pushed TC suppression from owner c-1 (replaces local TC apply) ----
        if (c > 0) {
            if (wave == 0) {
                if (lane == 0) { while (A_LD(&ctrl[PFLAG + c * 32]) != 1) {} }
                if (lane < WPC) kwsh[lane] = A_LD(&pusha[c * KSTRIDE + lane]);
            }
            __syncthreads();
            if (t < WPC) {
                ull s = kwsh[t];
                amask[2 * t]     &= ~(unsigned)s;
                amask[2 * t + 1] &= ~(unsigned)(s >> 32);
            }
            __syncthreads();
        }

        // ---- scan own chunk (wave 0): TD ballot fixpoint, then publish ----
        if (wave == 0) {
            ull alive[WPC];
            #pragma unroll
            for (int w = 0; w < WPC; ++w)
                alive[w] = (ull)amask[2 * w] | ((ull)amask[2 * w + 1] << 32);
            const ull* T = TDs;
            #pragma unroll
            for (int w = 0; w < WPC; ++w) {
                ull word = alive[w];
                if (!word) continue;
                ull Tc[WPC];
                #pragma unroll
                for (int j = 0; j < WPC; ++j)
                    if (j >= w) Tc[j] = T[w * 512 + j * 64 + lane];
                ull td = Tc[w];
                ull a2 = word, kept = 0;
                while (a2 & ~kept) {
                    bool al = (a2 >> lane) & 1;
                    bool kp = (kept >> lane) & 1;
                    ull nk = __ballot(al && !kp && ((td & a2) == 0));
                    ull nd = __ballot(al && !kp && ((td & kept) != 0));
                    kept |= nk;
                    a2 &= ~nd;
                }
                alive[w] = kept;
                #pragma unroll
                for (int j = 0; j < WPC; ++j) {
                    if (j <= w) continue;
                    if (!alive[j]) continue;
                    alive[j] &= ~__ballot((Tc[j] & kept) != 0);
                }
            }
            if (lane == 0) {
                #pragma unroll
                for (int w = 0; w < WPC; ++w) {
                    A_ST(&keptg[c * KSTRIDE + w], alive[w]);
                    amask[2 * w]     = (unsigned)alive[w];
                    amask[2 * w + 1] = (unsigned)(alive[w] >> 32);
                }
                A_STR(&ctrl[c * 32], 1);          // release orders the 8 stores
            }
        }
        __syncthreads();

        // ---- producer push: TC apply for chunk c+1, publish suppression ----
        if (c + 1 < nchv) {
            if (wave < WPC) {
                ull kw[WPC];
                #pragma unroll
                for (int w = 0; w < WPC; ++w)
                    kw[w] = (ull)amask[2 * w] | ((ull)amask[2 * w + 1] << 32);
                bool dead = false;
                #pragma unroll
                for (int w = 0; w < WPC; ++w) {
                    if (kw[w]) dead |= (TCs[w * 512 + wave * 64 + lane] & kw[w]) != 0ull;
                }
                ull d = __ballot(dead);
                if (lane == 0) darr[wave] = d;
            }
            __syncthreads();
            if (t == 0) {
                #pragma unroll
                for (int w = 0; w < WPC; ++w)
                    A_ST(&pusha[(c + 1) * KSTRIDE + w], darr[w]);
                A_STR(&ctrl[PFLAG + (c + 1) * 32], 1);   // release orders them
            }
        }
        __syncthreads();
    } else {
        if (t < 16) amask[t] = 0u;
        __syncthreads();
    }

    // ---- epilogue: write own 512 output rows ----
    if (t < CH) {
        int j = c * CH + t;
        bool kept = (amask[t >> 5] >> (t & 31)) & 1u;
        float4 b = boxes4[j];
        float s = scores[j];
        out[j * 5 + 0] = kept ? b.x : 0.0f;
        out[j * 5 + 1] = kept ? b.y : 0.0f;
        out[j * 5 + 2] = kept ? b.z : 0.0f;
        out[j * 5 + 3] = kept ? b.w : 0.0f;
        out[j * 5 + 4] = kept ? s   : 0.0f;
    }
}

extern "C" void kernel_launch(void* const* d_in, const int* in_sizes, int n_in,
                              void* d_out, int out_size, void* d_ws, size_t ws_size,
                              hipStream_t stream) {
    const float* in = (const float*)d_in[0];
    char* ws = (char*)d_ws;
    ull* TB        = (ull*)(ws + OFF_TB);
    ull* TC        = (ull*)(ws + OFF_TC);
    ull* TD        = (ull*)(ws + OFF_TD);
    float4* boxes4 = (float4*)(ws + OFF_BOXES);
    float* scores  = (float*)(ws + OFF_SCORES);
    int* ctrl      = (int*)(ws + OFF_CTRL);
    ull* keptg     = (ull*)(ws + OFF_KEPT);
    ull* pusha     = (ull*)(ws + OFF_PUSH);
    float* out     = (float*)d_out;

    k123_rank_scatter<<<256, 256, 0, stream>>>(in, boxes4, scores, ctrl);
    k4_build<<<2176, 256, 0, stream>>>(boxes4, scores, TB, TC, TD);
    k5_nms<<<NCH, 1024, 0, stream>>>(boxes4, scores, TB, TC, TD, keptg, pusha, ctrl, out);
}